// Round 9
// baseline (242.894 us; speedup 1.0000x reference)
//
#include <hip/hip_runtime.h>

#define N_ENTITIES 100000
#define N_USERS 50000
#define CHANNEL 64
#define N_RELATIONS 16
#define N_FACTORS 4
#define N_EDGES 1600000
#define N_INTER 1000000
#define TMASK ((1 << 17) - 1)

// buckets of 64 rows (scatter and gather granularity)
#define BSH 6
#define BSZ 64
#define NBE 1563      // ceil(100000/64)
#define NBU 782       // ceil(50000/64)
#define CAP_E 1536
#define CAP_U 1792
#define TILE_E 4096
#define TILE_U 4096
#define NCONV 6250    // N_ENTITIES*CHANNEL/4 / 256
#define NHIST 256     // hist blocks inside prep kernel
// L2 chunking: 4 chunks x 25000 entity rows (3.2 MB bf16 each, fits XCD L2)
#define NCHUNK 4
#define CHUNK_ROWS 25000

typedef unsigned short u16;

__device__ __forceinline__ float wave_reduce_sum(float p) {
    #pragma unroll
    for (int off = 32; off > 0; off >>= 1) p += __shfl_xor(p, off);
    return p;
}

// block-wide (1024 thr) inclusive scan via per-wave shfl scans; total in wsum[15]
__device__ __forceinline__ int block_scan_incl(int v, int* wsum) {
    int lane = threadIdx.x & 63, wid = threadIdx.x >> 6;
    int x = v;
    #pragma unroll
    for (int off = 1; off < 64; off <<= 1) {
        int y = __shfl_up(x, off);
        if (lane >= off) x += y;
    }
    __syncthreads();
    if (lane == 63) wsum[wid] = x;
    __syncthreads();
    if (wid == 0) {
        int s = (lane < 16) ? wsum[lane] : 0;
        #pragma unroll
        for (int off = 1; off < 16; off <<= 1) {
            int y = __shfl_up(s, off);
            if (lane >= off) s += y;
        }
        if (lane < 16) wsum[lane] = s;
    }
    __syncthreads();
    return x + (wid ? wsum[wid - 1] : 0);
}

__device__ __forceinline__ u16 f32_to_bf16_rne(float x) {
    unsigned u = __float_as_uint(x);
    return (u16)((u + 0x7FFFu + ((u >> 16) & 1u)) >> 16);
}

template <bool BF16>
__device__ __forceinline__ float ldrow(const float* __restrict__ e32,
                                       const u16* __restrict__ e16,
                                       int row, int lane) {
    if (BF16) return __uint_as_float(((unsigned)e16[(size_t)row * CHANNEL + lane]) << 16);
    return e32[(size_t)row * CHANNEL + lane];
}

// 256-thread 256-bin inclusive scan (4 waves, shfl). hist read-only.
__device__ __forceinline__ void scan256(const int* s_hist, int* s_scan,
                                        int* s_wp, int* wtot) {
    int tid = threadIdx.x;
    int lane = tid & 63, wv = tid >> 6;
    int c = s_hist[tid];
    int x = c;
    #pragma unroll
    for (int off = 1; off < 64; off <<= 1) {
        int y = __shfl_up(x, off);
        if (lane >= off) x += y;
    }
    if (lane == 63) wtot[wv] = x;
    __syncthreads();
    if (wv >= 1) x += wtot[0];
    if (wv >= 2) x += wtot[1];
    if (wv >= 3) x += wtot[2];
    s_scan[tid] = x;
    s_wp[tid]   = x - c;
    __syncthreads();
}

// ---------------------------------------------------------------------------
// disen = softmax(disen_weight_att, axis=-1) @ weight   [4 x 64]
// ---------------------------------------------------------------------------
__device__ __forceinline__ void disen_body(const float* __restrict__ dwa,
                                           const float* __restrict__ weight,
                                           float* __restrict__ disen) {
    int f = threadIdx.x >> 6;
    int c = threadIdx.x & 63;
    float m = -INFINITY;
    #pragma unroll
    for (int r = 0; r < N_RELATIONS; ++r) m = fmaxf(m, dwa[f * N_RELATIONS + r]);
    float denom = 0.f, acc = 0.f;
    #pragma unroll
    for (int r = 0; r < N_RELATIONS; ++r) {
        float e = expf(dwa[f * N_RELATIONS + r] - m);
        denom += e;
        acc += e * weight[r * CHANNEL + c];
    }
    disen[f * CHANNEL + c] = acc / denom;
}

__global__ void disen_kernel(const float* __restrict__ dwa,
                             const float* __restrict__ weight,
                             float* __restrict__ disen) {
    disen_body(dwa, weight, disen);
}

// ---------------------------------------------------------------------------
// PREP: blocks [0,NCONV) bf16-convert; block NCONV disen; rest histogram.
// Independent work -> overlapped in one launch.
// ---------------------------------------------------------------------------
__global__ __launch_bounds__(256) void prep_kernel(
    const float* __restrict__ src, u16* __restrict__ dst,
    const float* __restrict__ dwa, const float* __restrict__ weight,
    float* __restrict__ disen,
    const int* __restrict__ head, const int* __restrict__ irows,
    int* __restrict__ wp_e, int* __restrict__ wp_u) {
    __shared__ int lh[NBE + NBU];
    int bid = blockIdx.x;
    int tid = threadIdx.x;
    if (bid < NCONV) {
        int i = bid * 256 + tid;
        float4 v = ((const float4*)src)[i];
        ushort4 o;
        o.x = f32_to_bf16_rne(v.x);
        o.y = f32_to_bf16_rne(v.y);
        o.z = f32_to_bf16_rne(v.z);
        o.w = f32_to_bf16_rne(v.w);
        ((ushort4*)dst)[i] = o;
        return;
    }
    if (bid == NCONV) { disen_body(dwa, weight, disen); return; }
    // histogram blocks
    for (int i = tid; i < NBE + NBU; i += 256) lh[i] = 0;
    __syncthreads();
    const int NTOT = N_EDGES + N_INTER;
    int hb = bid - NCONV - 1;
    for (int i = hb * 256 + tid; i < NTOT; i += NHIST * 256) {
        if (i < N_EDGES) atomicAdd(&lh[head[i] >> BSH], 1);
        else             atomicAdd(&lh[NBE + (irows[i - N_EDGES] >> BSH)], 1);
    }
    __syncthreads();
    for (int i = tid; i < NBE + NBU; i += 256) {
        int c = lh[i];
        if (c) {
            if (i < NBE) atomicAdd(&wp_e[i], c);
            else         atomicAdd(&wp_u[i - NBE], c);
        }
    }
}

// fallback prep without bf16 conversion
__global__ __launch_bounds__(1024) void hist_kernel(
    const int* __restrict__ head, const int* __restrict__ irows,
    int* __restrict__ wp_e, int* __restrict__ wp_u) {
    __shared__ int lh[NBE + NBU];
    int tid = threadIdx.x;
    for (int i = tid; i < NBE + NBU; i += 1024) lh[i] = 0;
    __syncthreads();
    const int NTOT = N_EDGES + N_INTER;
    for (int i = blockIdx.x * 1024 + tid; i < NTOT; i += gridDim.x * 1024) {
        if (i < N_EDGES) atomicAdd(&lh[head[i] >> BSH], 1);
        else             atomicAdd(&lh[NBE + (irows[i - N_EDGES] >> BSH)], 1);
    }
    __syncthreads();
    for (int i = tid; i < NBE + NBU; i += 1024) {
        int c = lh[i];
        if (c) {
            if (i < NBE) atomicAdd(&wp_e[i], c);
            else         atomicAdd(&wp_u[i - NBE], c);
        }
    }
}

// ---------------------------------------------------------------------------
// One-block exclusive scans: edges (1563, two chunks) and users (782).
// ---------------------------------------------------------------------------
__global__ __launch_bounds__(1024) void scan_kernel(
    int* __restrict__ wp_e, int* __restrict__ coff_e,
    int* __restrict__ wp_u, int* __restrict__ coff_u) {
    __shared__ int wsum[16];
    int tid = threadIdx.x;
    int c0 = wp_e[tid];
    int incl0 = block_scan_incl(c0, wsum);
    int tot0 = wsum[15];
    int i1 = 1024 + tid;
    int c1 = (i1 < NBE) ? wp_e[i1] : 0;
    int incl1 = block_scan_incl(c1, wsum) + tot0;
    int cu = (tid < NBU) ? wp_u[tid] : 0;
    int inclu = block_scan_incl(cu, wsum);
    { int ex = incl0 - c0; coff_e[tid] = ex; wp_e[tid] = ex; }
    if (i1 < NBE) { int ex = incl1 - c1; coff_e[i1] = ex; wp_e[i1] = ex; }
    if (tid == 0) coff_e[NBE] = N_EDGES;
    if (tid < NBU) { int ex = inclu - cu; coff_u[tid] = ex; wp_u[tid] = ex; }
    if (tid == 0) coff_u[NBU] = N_INTER;
}

// ---------------------------------------------------------------------------
// Edge multisplit scatter. Payload: (head&63)<<21 | (et-1)<<17 | tail.
// ---------------------------------------------------------------------------
__global__ __launch_bounds__(1024) void scatter_edge_kernel(
    const int* __restrict__ head, const int* __restrict__ tail,
    const int* __restrict__ etype,
    int* __restrict__ wp, int* __restrict__ pay_g) {
    __shared__ int s_hist[NBE], s_lofs[NBE], s_gbase[NBE];
    __shared__ int s_pay[TILE_E];
    __shared__ int s_dest[TILE_E];
    __shared__ int wsum[16];
    int tid = threadIdx.x;
    int g0 = blockIdx.x * TILE_E;
    int tilecnt = min(TILE_E, N_EDGES - g0);
    for (int i = tid; i < NBE; i += 1024) s_hist[i] = 0;
    int cb[4], pp[4], rk[4];
    __syncthreads();
    #pragma unroll
    for (int j = 0; j < 4; ++j) {
        int s = j * 1024 + tid;
        if (s < tilecnt) {
            int i = g0 + s;
            int h = head[i];
            cb[j] = h >> BSH;
            pp[j] = ((h & (BSZ - 1)) << 21) | ((etype[i] - 1) << 17) | tail[i];
        } else cb[j] = -1;
    }
    #pragma unroll
    for (int j = 0; j < 4; ++j)
        if (cb[j] >= 0) rk[j] = atomicAdd(&s_hist[cb[j]], 1);
    __syncthreads();
    int c0 = s_hist[tid];
    int incl0 = block_scan_incl(c0, wsum);
    int tot0 = wsum[15];
    int i1 = 1024 + tid;
    int c1 = (i1 < NBE) ? s_hist[i1] : 0;
    int incl1 = block_scan_incl(c1, wsum) + tot0;
    {
        int ex = incl0 - c0;
        s_lofs[tid] = ex;
        if (c0 > 0) s_gbase[tid] = atomicAdd(&wp[tid], c0) - ex;
    }
    if (i1 < NBE) {
        int ex = incl1 - c1;
        s_lofs[i1] = ex;
        if (c1 > 0) s_gbase[i1] = atomicAdd(&wp[i1], c1) - ex;
    }
    __syncthreads();
    #pragma unroll
    for (int j = 0; j < 4; ++j) {
        if (cb[j] >= 0) {
            int slot = s_lofs[cb[j]] + rk[j];
            s_pay[slot]  = pp[j];
            s_dest[slot] = s_gbase[cb[j]] + slot;
        }
    }
    __syncthreads();
    #pragma unroll
    for (int j = 0; j < 4; ++j) {
        int s = j * 1024 + tid;
        if (s < tilecnt) pay_g[s_dest[s]] = s_pay[s];
    }
}

// ---------------------------------------------------------------------------
// Interaction multisplit scatter. PayloadA: (row&63)<<17 | col; PayloadB: val.
// ---------------------------------------------------------------------------
__global__ __launch_bounds__(1024) void scatter_inter_kernel(
    const int* __restrict__ irows, const int* __restrict__ icols,
    const float* __restrict__ vals,
    int* __restrict__ wp, int* __restrict__ payA_g, float* __restrict__ payB_g) {
    __shared__ int s_hist[NBU], s_lofs[NBU], s_gbase[NBU];
    __shared__ int s_pay[TILE_U];
    __shared__ float s_val[TILE_U];
    __shared__ int s_dest[TILE_U];
    __shared__ int wsum[16];
    int tid = threadIdx.x;
    int g0 = blockIdx.x * TILE_U;
    int tilecnt = min(TILE_U, N_INTER - g0);
    for (int i = tid; i < NBU; i += 1024) s_hist[i] = 0;
    int cb[4], pp[4], rk[4];
    float vv[4];
    __syncthreads();
    #pragma unroll
    for (int j = 0; j < 4; ++j) {
        int s = j * 1024 + tid;
        if (s < tilecnt) {
            int i = g0 + s;
            int u = irows[i];
            cb[j] = u >> BSH;
            pp[j] = ((u & (BSZ - 1)) << 17) | icols[i];
            vv[j] = vals[i];
        } else cb[j] = -1;
    }
    #pragma unroll
    for (int j = 0; j < 4; ++j)
        if (cb[j] >= 0) rk[j] = atomicAdd(&s_hist[cb[j]], 1);
    __syncthreads();
    int c0 = (tid < NBU) ? s_hist[tid] : 0;
    int incl0 = block_scan_incl(c0, wsum);
    if (tid < NBU) {
        int ex = incl0 - c0;
        s_lofs[tid] = ex;
        if (c0 > 0) s_gbase[tid] = atomicAdd(&wp[tid], c0) - ex;
    }
    __syncthreads();
    #pragma unroll
    for (int j = 0; j < 4; ++j) {
        if (cb[j] >= 0) {
            int slot = s_lofs[cb[j]] + rk[j];
            s_pay[slot]  = pp[j];
            s_val[slot]  = vv[j];
            s_dest[slot] = s_gbase[cb[j]] + slot;
        }
    }
    __syncthreads();
    #pragma unroll
    for (int j = 0; j < 4; ++j) {
        int s = j * 1024 + tid;
        if (s < tilecnt) {
            payA_g[s_dest[s]] = s_pay[s];
            payB_g[s_dest[s]] = s_val[s];
        }
    }
}

// ---------------------------------------------------------------------------
// FUSED gather, chunk-ordered: sort bucket run by key=(chunk<<6)|row, then
// sweep chunks with acc[16] in REGISTERS (no LDS atomics). All co-resident
// blocks touch the same 3.2 MB table chunk together -> L2-resident rows.
// 256 threads, <=20 KB LDS, 8 blocks/CU.
// ---------------------------------------------------------------------------
template <bool BF16>
__global__ __launch_bounds__(256, 8) void gather_kernel(
    const float* __restrict__ entity_emb,
    const u16* __restrict__ emb16,
    const float* __restrict__ weight,
    const float* __restrict__ user_emb,
    const float* __restrict__ latent_emb,
    const float* __restrict__ disen,
    const int* __restrict__ coff_e,
    const int* __restrict__ pay_e,
    const int* __restrict__ coff_u,
    const int* __restrict__ payA_u,
    const float* __restrict__ payB_u,
    float* __restrict__ entity_agg,
    float* __restrict__ user_agg) {
    __shared__ __align__(16) char smem[19520];
    int tid = threadIdx.x;
    int wv = tid >> 6, lane = tid & 63;
    int bid = blockIdx.x;

    if (bid < NBE) {
        // ------------------ edge path ------------------
        float* w65    = (float*)smem;              // 1040
        float* s_attv = w65 + 1040;                // 1024
        int*   s_pay  = (int*)(s_attv + 1024);     // CAP_E
        int*   s_hist = s_pay + CAP_E;             // 256
        int*   s_scan = s_hist + 256;              // 256
        int*   s_wp   = s_scan + 256;              // 256
        int*   wtot   = s_wp + 256;                // 4

        for (int i = tid; i < N_RELATIONS * CHANNEL; i += 256)
            w65[(i >> 6) * 65 + (i & 63)] = weight[i];
        s_hist[tid] = 0;
        int kbeg = coff_e[bid];
        int n = min(coff_e[bid + 1] - kbeg, CAP_E);
        __syncthreads();

        // pass 1: count keys
        for (int s = tid; s < n; s += 256) {
            int p = pay_e[kbeg + s];
            int key = ((int)((unsigned)(p & TMASK) / CHUNK_ROWS) << 6) | (p >> 21);
            atomicAdd(&s_hist[key], 1);
        }
        __syncthreads();
        scan256(s_hist, s_scan, s_wp, wtot);
        // pass 2: place (payload L2-hot)
        for (int s = tid; s < n; s += 256) {
            int p = pay_e[kbeg + s];
            int key = ((int)((unsigned)(p & TMASK) / CHUNK_ROWS) << 6) | (p >> 21);
            s_pay[atomicAdd(&s_wp[key], 1)] = p;
        }

        // att table: wave wv computes rows [wv*16, wv*16+16)
        int r = lane >> 2, q = lane & 3;
        for (int t = 0; t < 16; ++t) {
            int le = wv * 16 + t;
            int ge = bid * BSZ + le;
            if (ge >= N_ENTITIES) break;
            float eh = entity_emb[(size_t)ge * CHANNEL + lane];
            float p = 0.f;
            #pragma unroll
            for (int j = 0; j < 16; ++j)
                p += __shfl(eh, q * 16 + j) * w65[r * 65 + q * 16 + j];
            p += __shfl_xor(p, 1);
            p += __shfl_xor(p, 2);
            if (q == 0) s_attv[(le << 4) + r] = 1.f / (1.f + expf(-p));
        }
        __syncthreads();

        float acc[16];
        #pragma unroll
        for (int t = 0; t < 16; ++t) acc[t] = 0.f;

        for (int c = 0; c < NCHUNK; ++c) {
            #pragma unroll
            for (int t = 0; t < 16; ++t) {
                int le = wv * 16 + t;
                int key = (c << 6) | le;
                int ke = s_scan[key];
                int k = ke - s_hist[key];
                float a = acc[t];
                for (; k + 4 <= ke; k += 4) {
                    int p0 = s_pay[k], p1 = s_pay[k + 1];
                    int p2 = s_pay[k + 2], p3 = s_pay[k + 3];
                    float v0 = ldrow<BF16>(entity_emb, emb16, p0 & TMASK, lane);
                    float v1 = ldrow<BF16>(entity_emb, emb16, p1 & TMASK, lane);
                    float v2 = ldrow<BF16>(entity_emb, emb16, p2 & TMASK, lane);
                    float v3 = ldrow<BF16>(entity_emb, emb16, p3 & TMASK, lane);
                    int e0 = (p0 >> 17) & 15, e1 = (p1 >> 17) & 15;
                    int e2 = (p2 >> 17) & 15, e3 = (p3 >> 17) & 15;
                    a += s_attv[(le << 4) + e0] * v0 * w65[e0 * 65 + lane];
                    a += s_attv[(le << 4) + e1] * v1 * w65[e1 * 65 + lane];
                    a += s_attv[(le << 4) + e2] * v2 * w65[e2 * 65 + lane];
                    a += s_attv[(le << 4) + e3] * v3 * w65[e3 * 65 + lane];
                }
                for (; k < ke; ++k) {
                    int p0 = s_pay[k];
                    int e0 = (p0 >> 17) & 15;
                    float v0 = ldrow<BF16>(entity_emb, emb16, p0 & TMASK, lane);
                    a += s_attv[(le << 4) + e0] * v0 * w65[e0 * 65 + lane];
                }
                acc[t] = a;
            }
        }

        #pragma unroll
        for (int t = 0; t < 16; ++t) {
            int le = wv * 16 + t;
            int ge = bid * BSZ + le;
            if (ge < N_ENTITIES) {
                int deg = s_hist[le] + s_hist[64 + le] + s_hist[128 + le] + s_hist[192 + le];
                entity_agg[(size_t)ge * CHANNEL + lane] = acc[t] / fmaxf((float)deg, 1.0f);
            }
        }
    } else {
        // ------------------ user path ------------------
        int*   s_pay  = (int*)smem;                // CAP_U
        float* s_val  = (float*)(s_pay + CAP_U);   // CAP_U
        float* s_lat  = s_val + CAP_U;             // 256
        float* s_dis  = s_lat + 256;               // 256
        int*   s_hist = (int*)(s_dis + 256);       // 256
        int*   s_scan = s_hist + 256;              // 256
        int*   s_wp   = s_scan + 256;              // 256
        int*   wtot   = s_wp + 256;                // 4

        s_hist[tid] = 0;
        if (tid < N_FACTORS * CHANNEL) {
            s_lat[tid] = latent_emb[tid];
            s_dis[tid] = disen[tid];
        }
        int b = bid - NBE;
        int kbeg = coff_u[b];
        int n = min(coff_u[b + 1] - kbeg, CAP_U);
        __syncthreads();

        for (int s = tid; s < n; s += 256) {
            int p = payA_u[kbeg + s];
            int key = ((int)((unsigned)(p & TMASK) / CHUNK_ROWS) << 6) | (p >> 17);
            atomicAdd(&s_hist[key], 1);
        }
        __syncthreads();
        scan256(s_hist, s_scan, s_wp, wtot);
        for (int s = tid; s < n; s += 256) {
            int p = payA_u[kbeg + s];
            int key = ((int)((unsigned)(p & TMASK) / CHUNK_ROWS) << 6) | (p >> 17);
            int slot = atomicAdd(&s_wp[key], 1);
            s_pay[slot] = p & TMASK;
            s_val[slot] = payB_u[kbeg + s];
        }
        __syncthreads();

        float acc[16];
        #pragma unroll
        for (int t = 0; t < 16; ++t) acc[t] = 0.f;

        for (int c = 0; c < NCHUNK; ++c) {
            #pragma unroll
            for (int t = 0; t < 16; ++t) {
                int lu = wv * 16 + t;
                int key = (c << 6) | lu;
                int ke = s_scan[key];
                int k = ke - s_hist[key];
                float a = acc[t];
                for (; k + 4 <= ke; k += 4) {
                    float v0 = ldrow<BF16>(entity_emb, emb16, s_pay[k],     lane);
                    float v1 = ldrow<BF16>(entity_emb, emb16, s_pay[k + 1], lane);
                    float v2 = ldrow<BF16>(entity_emb, emb16, s_pay[k + 2], lane);
                    float v3 = ldrow<BF16>(entity_emb, emb16, s_pay[k + 3], lane);
                    a += s_val[k] * v0 + s_val[k + 1] * v1 + s_val[k + 2] * v2 + s_val[k + 3] * v3;
                }
                for (; k < ke; ++k)
                    a += s_val[k] * ldrow<BF16>(entity_emb, emb16, s_pay[k], lane);
                acc[t] = a;
            }
        }

        #pragma unroll
        for (int t = 0; t < 16; ++t) {
            int lu = wv * 16 + t;
            int gu = b * BSZ + lu;
            if (gu < N_USERS) {
                float ue = user_emb[(size_t)gu * CHANNEL + lane];
                float s[N_FACTORS];
                #pragma unroll
                for (int f = 0; f < N_FACTORS; ++f)
                    s[f] = wave_reduce_sum(ue * s_lat[f * CHANNEL + lane]);
                float m = fmaxf(fmaxf(s[0], s[1]), fmaxf(s[2], s[3]));
                float d = 0.f;
                #pragma unroll
                for (int f = 0; f < N_FACTORS; ++f) { s[f] = expf(s[f] - m); d += s[f]; }
                float gate = 0.f;
                #pragma unroll
                for (int f = 0; f < N_FACTORS; ++f)
                    gate += s_dis[f * CHANNEL + lane] * (s[f] / d);
                user_agg[(size_t)gu * CHANNEL + lane] = acc[t] * gate + acc[t];
            }
        }
    }
}

extern "C" void kernel_launch(void* const* d_in, const int* in_sizes, int n_in,
                              void* d_out, int out_size, void* d_ws, size_t ws_size,
                              hipStream_t stream) {
    const float* entity_emb    = (const float*)d_in[0];
    const float* user_emb      = (const float*)d_in[1];
    const float* latent_emb    = (const float*)d_in[2];
    const float* weight        = (const float*)d_in[3];
    const float* dwa           = (const float*)d_in[4];
    const float* interact_vals = (const float*)d_in[5];
    const int*   head          = (const int*)d_in[6];
    const int*   tail          = (const int*)d_in[7];
    const int*   edge_type     = (const int*)d_in[8];
    const int*   irows         = (const int*)d_in[9];
    const int*   icols         = (const int*)d_in[10];

    float* entity_agg = (float*)d_out;                                 // [N_ENTITIES,64]
    float* user_agg   = (float*)d_out + (size_t)N_ENTITIES * CHANNEL;  // [N_USERS,64]

    // workspace layout
    int*   wp_e   = (int*)d_ws;                   // NBE
    int*   wp_u   = wp_e + NBE;                   // NBU
    int*   coff_e = wp_u + NBU;                   // NBE+1
    int*   coff_u = coff_e + NBE + 1;             // NBU+1
    int*   pay_e  = coff_u + NBU + 1;             // N_EDGES
    int*   payA_u = pay_e + N_EDGES;              // N_INTER
    float* payB_u = (float*)(payA_u + N_INTER);   // N_INTER
    float* disen  = payB_u + N_INTER;             // 4*64
    u16*   emb16  = (u16*)(disen + N_FACTORS * CHANNEL);  // N_ENTITIES*64

    size_t need_bf16 = (size_t)((char*)(emb16 + (size_t)N_ENTITIES * CHANNEL) - (char*)d_ws);
    bool use_bf16 = (ws_size >= need_bf16);
    if (!use_bf16) emb16 = (u16*)d_ws;   // unused dummy

    hipMemsetAsync(wp_e, 0, (size_t)(NBE + NBU) * sizeof(int), stream);

    if (use_bf16) {
        prep_kernel<<<NCONV + 1 + NHIST, 256, 0, stream>>>(
            entity_emb, emb16, dwa, weight, disen, head, irows, wp_e, wp_u);
    } else {
        disen_kernel<<<1, 256, 0, stream>>>(dwa, weight, disen);
        hist_kernel<<<128, 1024, 0, stream>>>(head, irows, wp_e, wp_u);
    }

    scan_kernel<<<1, 1024, 0, stream>>>(wp_e, coff_e, wp_u, coff_u);

    scatter_edge_kernel<<<(N_EDGES + TILE_E - 1) / TILE_E, 1024, 0, stream>>>(
        head, tail, edge_type, wp_e, pay_e);
    scatter_inter_kernel<<<(N_INTER + TILE_U - 1) / TILE_U, 1024, 0, stream>>>(
        irows, icols, interact_vals, wp_u, payA_u, payB_u);

    if (use_bf16) {
        gather_kernel<true><<<NBE + NBU, 256, 0, stream>>>(
            entity_emb, emb16, weight, user_emb, latent_emb, disen,
            coff_e, pay_e, coff_u, payA_u, payB_u, entity_agg, user_agg);
    } else {
        gather_kernel<false><<<NBE + NBU, 256, 0, stream>>>(
            entity_emb, emb16, weight, user_emb, latent_emb, disen,
            coff_e, pay_e, coff_u, payA_u, payB_u, entity_agg, user_agg);
    }
}

// Round 10
// 198.643 us; speedup vs baseline: 1.2228x; 1.2228x over previous
//
#include <hip/hip_runtime.h>

#define N_ENTITIES 100000
#define N_USERS 50000
#define CHANNEL 64
#define N_RELATIONS 16
#define N_FACTORS 4
#define N_EDGES 1600000
#define N_INTER 1000000
#define TMASK ((1 << 17) - 1)

// buckets of 64 rows (scatter and gather granularity)
#define BSH 6
#define BSZ 64
#define NBE 1563      // ceil(100000/64)
#define NBU 782       // ceil(50000/64)
#define CAP_E 1536
#define CAP_U 1792
#define TILE_E 4096
#define TILE_U 4096
#define NTBE 391      // ceil(N_EDGES/TILE_E)
#define NTBU 245      // ceil(N_INTER/TILE_U)
#define NCONV 6250    // N_ENTITIES*CHANNEL/4 / 256
#define NHIST 256     // hist blocks inside prep kernel

typedef unsigned short u16;

__device__ __forceinline__ float wave_reduce_sum(float p) {
    #pragma unroll
    for (int off = 32; off > 0; off >>= 1) p += __shfl_xor(p, off);
    return p;
}

// block-wide (1024 thr) inclusive scan via per-wave shfl scans; total in wsum[15]
__device__ __forceinline__ int block_scan_incl(int v, int* wsum) {
    int lane = threadIdx.x & 63, wid = threadIdx.x >> 6;
    int x = v;
    #pragma unroll
    for (int off = 1; off < 64; off <<= 1) {
        int y = __shfl_up(x, off);
        if (lane >= off) x += y;
    }
    __syncthreads();
    if (lane == 63) wsum[wid] = x;
    __syncthreads();
    if (wid == 0) {
        int s = (lane < 16) ? wsum[lane] : 0;
        #pragma unroll
        for (int off = 1; off < 16; off <<= 1) {
            int y = __shfl_up(s, off);
            if (lane >= off) s += y;
        }
        if (lane < 16) wsum[lane] = s;
    }
    __syncthreads();
    return x + (wid ? wsum[wid - 1] : 0);
}

__device__ __forceinline__ u16 f32_to_bf16_rne(float x) {
    unsigned u = __float_as_uint(x);
    return (u16)((u + 0x7FFFu + ((u >> 16) & 1u)) >> 16);
}

template <bool BF16>
__device__ __forceinline__ float ldrow(const float* __restrict__ e32,
                                       const u16* __restrict__ e16,
                                       int row, int lane) {
    if (BF16) return __uint_as_float(((unsigned)e16[(size_t)row * CHANNEL + lane]) << 16);
    return e32[(size_t)row * CHANNEL + lane];
}

// ---------------------------------------------------------------------------
// disen = softmax(disen_weight_att, axis=-1) @ weight   [4 x 64]
// ---------------------------------------------------------------------------
__device__ __forceinline__ void disen_body(const float* __restrict__ dwa,
                                           const float* __restrict__ weight,
                                           float* __restrict__ disen) {
    int f = threadIdx.x >> 6;
    int c = threadIdx.x & 63;
    float m = -INFINITY;
    #pragma unroll
    for (int r = 0; r < N_RELATIONS; ++r) m = fmaxf(m, dwa[f * N_RELATIONS + r]);
    float denom = 0.f, acc = 0.f;
    #pragma unroll
    for (int r = 0; r < N_RELATIONS; ++r) {
        float e = expf(dwa[f * N_RELATIONS + r] - m);
        denom += e;
        acc += e * weight[r * CHANNEL + c];
    }
    disen[f * CHANNEL + c] = acc / denom;
}

__global__ void disen_kernel(const float* __restrict__ dwa,
                             const float* __restrict__ weight,
                             float* __restrict__ disen) {
    disen_body(dwa, weight, disen);
}

// ---------------------------------------------------------------------------
// PREP: blocks [0,NCONV) bf16-convert; block NCONV disen; rest histogram.
// ---------------------------------------------------------------------------
__global__ __launch_bounds__(256) void prep_kernel(
    const float* __restrict__ src, u16* __restrict__ dst,
    const float* __restrict__ dwa, const float* __restrict__ weight,
    float* __restrict__ disen,
    const int* __restrict__ head, const int* __restrict__ irows,
    int* __restrict__ wp_e, int* __restrict__ wp_u) {
    __shared__ int lh[NBE + NBU];
    int bid = blockIdx.x;
    int tid = threadIdx.x;
    if (bid < NCONV) {
        int i = bid * 256 + tid;
        float4 v = ((const float4*)src)[i];
        ushort4 o;
        o.x = f32_to_bf16_rne(v.x);
        o.y = f32_to_bf16_rne(v.y);
        o.z = f32_to_bf16_rne(v.z);
        o.w = f32_to_bf16_rne(v.w);
        ((ushort4*)dst)[i] = o;
        return;
    }
    if (bid == NCONV) { disen_body(dwa, weight, disen); return; }
    for (int i = tid; i < NBE + NBU; i += 256) lh[i] = 0;
    __syncthreads();
    const int NTOT = N_EDGES + N_INTER;
    int hb = bid - NCONV - 1;
    for (int i = hb * 256 + tid; i < NTOT; i += NHIST * 256) {
        if (i < N_EDGES) atomicAdd(&lh[head[i] >> BSH], 1);
        else             atomicAdd(&lh[NBE + (irows[i - N_EDGES] >> BSH)], 1);
    }
    __syncthreads();
    for (int i = tid; i < NBE + NBU; i += 256) {
        int c = lh[i];
        if (c) {
            if (i < NBE) atomicAdd(&wp_e[i], c);
            else         atomicAdd(&wp_u[i - NBE], c);
        }
    }
}

// fallback hist without bf16 conversion
__global__ __launch_bounds__(1024) void hist_kernel(
    const int* __restrict__ head, const int* __restrict__ irows,
    int* __restrict__ wp_e, int* __restrict__ wp_u) {
    __shared__ int lh[NBE + NBU];
    int tid = threadIdx.x;
    for (int i = tid; i < NBE + NBU; i += 1024) lh[i] = 0;
    __syncthreads();
    const int NTOT = N_EDGES + N_INTER;
    for (int i = blockIdx.x * 1024 + tid; i < NTOT; i += gridDim.x * 1024) {
        if (i < N_EDGES) atomicAdd(&lh[head[i] >> BSH], 1);
        else             atomicAdd(&lh[NBE + (irows[i - N_EDGES] >> BSH)], 1);
    }
    __syncthreads();
    for (int i = tid; i < NBE + NBU; i += 1024) {
        int c = lh[i];
        if (c) {
            if (i < NBE) atomicAdd(&wp_e[i], c);
            else         atomicAdd(&wp_u[i - NBE], c);
        }
    }
}

// ---------------------------------------------------------------------------
// One-block exclusive scans: edges (1563, two chunks) and users (782).
// ---------------------------------------------------------------------------
__global__ __launch_bounds__(1024) void scan_kernel(
    int* __restrict__ wp_e, int* __restrict__ coff_e,
    int* __restrict__ wp_u, int* __restrict__ coff_u) {
    __shared__ int wsum[16];
    int tid = threadIdx.x;
    int c0 = wp_e[tid];
    int incl0 = block_scan_incl(c0, wsum);
    int tot0 = wsum[15];
    int i1 = 1024 + tid;
    int c1 = (i1 < NBE) ? wp_e[i1] : 0;
    int incl1 = block_scan_incl(c1, wsum) + tot0;
    int cu = (tid < NBU) ? wp_u[tid] : 0;
    int inclu = block_scan_incl(cu, wsum);
    { int ex = incl0 - c0; coff_e[tid] = ex; wp_e[tid] = ex; }
    if (i1 < NBE) { int ex = incl1 - c1; coff_e[i1] = ex; wp_e[i1] = ex; }
    if (tid == 0) coff_e[NBE] = N_EDGES;
    if (tid < NBU) { int ex = inclu - cu; coff_u[tid] = ex; wp_u[tid] = ex; }
    if (tid == 0) coff_u[NBU] = N_INTER;
}

// ---------------------------------------------------------------------------
// MERGED multisplit scatter: blocks [0,NTBE) edge tiles; rest inter tiles.
// Edge payload: (head&63)<<21 | (et-1)<<17 | tail.
// Inter payloads: (row&63)<<17 | col ; val.
// ---------------------------------------------------------------------------
__global__ __launch_bounds__(1024) void scatter_kernel(
    const int* __restrict__ head, const int* __restrict__ tail,
    const int* __restrict__ etype,
    const int* __restrict__ irows, const int* __restrict__ icols,
    const float* __restrict__ vals,
    int* __restrict__ wp_e, int* __restrict__ pay_e,
    int* __restrict__ wp_u, int* __restrict__ payA_u, float* __restrict__ payB_u) {
    __shared__ __align__(16) char smem[58624];
    __shared__ int wsum[16];
    int tid = threadIdx.x;
    int bid = blockIdx.x;

    if (bid < NTBE) {
        int* s_hist  = (int*)smem;            // NBE
        int* s_lofs  = s_hist + NBE;          // NBE
        int* s_gbase = s_lofs + NBE;          // NBE
        int* s_pay   = s_gbase + NBE;         // TILE_E
        int* s_dest  = s_pay + TILE_E;        // TILE_E
        int g0 = bid * TILE_E;
        int tilecnt = min(TILE_E, N_EDGES - g0);
        for (int i = tid; i < NBE; i += 1024) s_hist[i] = 0;
        int cb[4], pp[4], rk[4];
        __syncthreads();
        #pragma unroll
        for (int j = 0; j < 4; ++j) {
            int s = j * 1024 + tid;
            if (s < tilecnt) {
                int i = g0 + s;
                int h = head[i];
                cb[j] = h >> BSH;
                pp[j] = ((h & (BSZ - 1)) << 21) | ((etype[i] - 1) << 17) | tail[i];
            } else cb[j] = -1;
        }
        #pragma unroll
        for (int j = 0; j < 4; ++j)
            if (cb[j] >= 0) rk[j] = atomicAdd(&s_hist[cb[j]], 1);
        __syncthreads();
        int c0 = s_hist[tid];
        int incl0 = block_scan_incl(c0, wsum);
        int tot0 = wsum[15];
        int i1 = 1024 + tid;
        int c1 = (i1 < NBE) ? s_hist[i1] : 0;
        int incl1 = block_scan_incl(c1, wsum) + tot0;
        {
            int ex = incl0 - c0;
            s_lofs[tid] = ex;
            if (c0 > 0) s_gbase[tid] = atomicAdd(&wp_e[tid], c0) - ex;
        }
        if (i1 < NBE) {
            int ex = incl1 - c1;
            s_lofs[i1] = ex;
            if (c1 > 0) s_gbase[i1] = atomicAdd(&wp_e[i1], c1) - ex;
        }
        __syncthreads();
        #pragma unroll
        for (int j = 0; j < 4; ++j) {
            if (cb[j] >= 0) {
                int slot = s_lofs[cb[j]] + rk[j];
                s_pay[slot]  = pp[j];
                s_dest[slot] = s_gbase[cb[j]] + slot;
            }
        }
        __syncthreads();
        #pragma unroll
        for (int j = 0; j < 4; ++j) {
            int s = j * 1024 + tid;
            if (s < tilecnt) pay_e[s_dest[s]] = s_pay[s];
        }
    } else {
        int*   s_hist  = (int*)smem;           // NBU
        int*   s_lofs  = s_hist + NBU;         // NBU
        int*   s_gbase = s_lofs + NBU;         // NBU
        int*   s_pay   = s_gbase + NBU;        // TILE_U
        float* s_val   = (float*)(s_pay + TILE_U);  // TILE_U
        int*   s_dest  = (int*)(s_val + TILE_U);    // TILE_U
        int g0 = (bid - NTBE) * TILE_U;
        int tilecnt = min(TILE_U, N_INTER - g0);
        for (int i = tid; i < NBU; i += 1024) s_hist[i] = 0;
        int cb[4], pp[4], rk[4];
        float vv[4];
        __syncthreads();
        #pragma unroll
        for (int j = 0; j < 4; ++j) {
            int s = j * 1024 + tid;
            if (s < tilecnt) {
                int i = g0 + s;
                int u = irows[i];
                cb[j] = u >> BSH;
                pp[j] = ((u & (BSZ - 1)) << 17) | icols[i];
                vv[j] = vals[i];
            } else cb[j] = -1;
        }
        #pragma unroll
        for (int j = 0; j < 4; ++j)
            if (cb[j] >= 0) rk[j] = atomicAdd(&s_hist[cb[j]], 1);
        __syncthreads();
        int c0 = (tid < NBU) ? s_hist[tid] : 0;
        int incl0 = block_scan_incl(c0, wsum);
        if (tid < NBU) {
            int ex = incl0 - c0;
            s_lofs[tid] = ex;
            if (c0 > 0) s_gbase[tid] = atomicAdd(&wp_u[tid], c0) - ex;
        }
        __syncthreads();
        #pragma unroll
        for (int j = 0; j < 4; ++j) {
            if (cb[j] >= 0) {
                int slot = s_lofs[cb[j]] + rk[j];
                s_pay[slot]  = pp[j];
                s_val[slot]  = vv[j];
                s_dest[slot] = s_gbase[cb[j]] + slot;
            }
        }
        __syncthreads();
        #pragma unroll
        for (int j = 0; j < 4; ++j) {
            int s = j * 1024 + tid;
            if (s < tilecnt) {
                payA_u[s_dest[s]] = s_pay[s];
                payB_u[s_dest[s]] = s_val[s];
            }
        }
    }
}

// ---------------------------------------------------------------------------
// FUSED gather (round-8 structure): block < NBE -> edge bucket; else user.
// 256 threads (4 waves x 16 rows). In-LDS counting sort by local row, then
// per-row register-accumulate segments. Nontemporal output stores.
// ---------------------------------------------------------------------------
template <bool BF16>
__global__ __launch_bounds__(256, 8) void gather_kernel(
    const float* __restrict__ entity_emb,
    const u16* __restrict__ emb16,
    const float* __restrict__ weight,
    const float* __restrict__ user_emb,
    const float* __restrict__ latent_emb,
    const float* __restrict__ disen,
    const int* __restrict__ coff_e,
    const int* __restrict__ pay_e,
    const int* __restrict__ coff_u,
    const int* __restrict__ payA_u,
    const float* __restrict__ payB_u,
    float* __restrict__ entity_agg,
    float* __restrict__ user_agg) {
    __shared__ __align__(16) char smem[16896];
    int tid = threadIdx.x;
    int wv = tid >> 6, lane = tid & 63;
    int bid = blockIdx.x;

    if (bid < NBE) {
        // ------------------ edge path ------------------
        float* w65    = (float*)smem;              // 1040
        float* s_attv = w65 + 1040;                // 1024
        int*   s_pay  = (int*)(s_attv + 1024);     // 1536
        int*   s_hist = s_pay + CAP_E;             // 64
        int*   s_scan = s_hist + 64;               // 64

        for (int i = tid; i < N_RELATIONS * CHANNEL; i += 256)
            w65[(i >> 6) * 65 + (i & 63)] = weight[i];
        if (tid < BSZ) s_hist[tid] = 0;
        int kbeg = coff_e[bid];
        int n = min(coff_e[bid + 1] - kbeg, CAP_E);
        __syncthreads();

        // stage + rank
        int myp[CAP_E / 256], myr[CAP_E / 256];
        #pragma unroll
        for (int j = 0; j < CAP_E / 256; ++j) {
            int s = j * 256 + tid;
            if (s < n) {
                int p = pay_e[kbeg + s];
                myp[j] = p;
                myr[j] = atomicAdd(&s_hist[p >> 21], 1);
            }
        }
        __syncthreads();
        if (wv == 0) {   // single-wave inclusive scan over 64 bins
            int x = s_hist[lane];
            #pragma unroll
            for (int off = 1; off < 64; off <<= 1) {
                int y = __shfl_up(x, off);
                if (lane >= off) x += y;
            }
            s_scan[lane] = x;
        }
        __syncthreads();
        #pragma unroll
        for (int j = 0; j < CAP_E / 256; ++j) {
            int s = j * 256 + tid;
            if (s < n) {
                int key = myp[j] >> 21;
                s_pay[s_scan[key] - s_hist[key] + myr[j]] = myp[j];
            }
        }

        // att table: wave wv computes rows [wv*16, wv*16+16)  (bf16 head rows)
        int r = lane >> 2, q = lane & 3;
        for (int t = 0; t < 16; ++t) {
            int le = wv * 16 + t;
            int ge = bid * BSZ + le;
            if (ge >= N_ENTITIES) break;
            float eh = ldrow<BF16>(entity_emb, emb16, ge, lane);
            float p = 0.f;
            #pragma unroll
            for (int j = 0; j < 16; ++j)
                p += __shfl(eh, q * 16 + j) * w65[r * 65 + q * 16 + j];
            p += __shfl_xor(p, 1);
            p += __shfl_xor(p, 2);
            if (q == 0) s_attv[(le << 4) + r] = 1.f / (1.f + expf(-p));
        }
        __syncthreads();

        #define EBODY(K) { \
            int pp = s_pay[K]; \
            int et = (pp >> 17) & 15; \
            float v = ldrow<BF16>(entity_emb, emb16, pp & TMASK, lane); \
            acc += s_attv[(le << 4) + et] * v * w65[et * 65 + lane]; }
        for (int t = 0; t < 16; ++t) {
            int le = wv * 16 + t;
            int ge = bid * BSZ + le;
            if (ge >= N_ENTITIES) break;
            int cnt = s_hist[le];
            int ke = s_scan[le];
            int k = ke - cnt;
            float acc = 0.f;
            for (; k + 4 <= ke; k += 4) {
                EBODY(k); EBODY(k + 1); EBODY(k + 2); EBODY(k + 3);
            }
            for (; k < ke; ++k) EBODY(k);
            __builtin_nontemporal_store(acc / fmaxf((float)cnt, 1.0f),
                                        &entity_agg[(size_t)ge * CHANNEL + lane]);
        }
        #undef EBODY
    } else {
        // ------------------ user path ------------------
        int*   s_pay  = (int*)smem;                // 1792
        float* s_val  = (float*)(s_pay + CAP_U);   // 1792
        float* s_lat  = s_val + CAP_U;             // 256
        float* s_dis  = s_lat + 256;               // 256
        int*   s_hist = (int*)(s_dis + 256);       // 64
        int*   s_scan = s_hist + 64;               // 64

        if (tid < BSZ) s_hist[tid] = 0;
        if (tid < N_FACTORS * CHANNEL) {
            s_lat[tid] = latent_emb[tid];
            s_dis[tid] = disen[tid];
        }
        int b = bid - NBE;
        int kbeg = coff_u[b];
        int n = min(coff_u[b + 1] - kbeg, CAP_U);
        __syncthreads();

        int myp[CAP_U / 256], myr[CAP_U / 256];
        float myv[CAP_U / 256];
        #pragma unroll
        for (int j = 0; j < CAP_U / 256; ++j) {
            int s = j * 256 + tid;
            if (s < n) {
                int p = payA_u[kbeg + s];
                myp[j] = p;
                myv[j] = payB_u[kbeg + s];
                myr[j] = atomicAdd(&s_hist[p >> 17], 1);
            }
        }
        __syncthreads();
        if (wv == 0) {
            int x = s_hist[lane];
            #pragma unroll
            for (int off = 1; off < 64; off <<= 1) {
                int y = __shfl_up(x, off);
                if (lane >= off) x += y;
            }
            s_scan[lane] = x;
        }
        __syncthreads();
        #pragma unroll
        for (int j = 0; j < CAP_U / 256; ++j) {
            int s = j * 256 + tid;
            if (s < n) {
                int key = myp[j] >> 17;
                int slot = s_scan[key] - s_hist[key] + myr[j];
                s_pay[slot] = myp[j] & TMASK;
                s_val[slot] = myv[j];
            }
        }
        __syncthreads();

        #define UBODY(K) { \
            float v = ldrow<BF16>(entity_emb, emb16, s_pay[K], lane); \
            acc += s_val[K] * v; }
        for (int t = 0; t < 16; ++t) {
            int lu = wv * 16 + t;
            int gu = b * BSZ + lu;
            if (gu >= N_USERS) break;
            int cnt = s_hist[lu];
            int ke = s_scan[lu];
            int k = ke - cnt;
            float acc = 0.f;
            for (; k + 4 <= ke; k += 4) {
                UBODY(k); UBODY(k + 1); UBODY(k + 2); UBODY(k + 3);
            }
            for (; k < ke; ++k) UBODY(k);

            float ue = user_emb[(size_t)gu * CHANNEL + lane];
            float s[N_FACTORS];
            #pragma unroll
            for (int f = 0; f < N_FACTORS; ++f)
                s[f] = wave_reduce_sum(ue * s_lat[f * CHANNEL + lane]);
            float m = fmaxf(fmaxf(s[0], s[1]), fmaxf(s[2], s[3]));
            float d = 0.f;
            #pragma unroll
            for (int f = 0; f < N_FACTORS; ++f) { s[f] = expf(s[f] - m); d += s[f]; }
            float gate = 0.f;
            #pragma unroll
            for (int f = 0; f < N_FACTORS; ++f)
                gate += s_dis[f * CHANNEL + lane] * (s[f] / d);
            __builtin_nontemporal_store(acc * gate + acc,
                                        &user_agg[(size_t)gu * CHANNEL + lane]);
        }
        #undef UBODY
    }
}

extern "C" void kernel_launch(void* const* d_in, const int* in_sizes, int n_in,
                              void* d_out, int out_size, void* d_ws, size_t ws_size,
                              hipStream_t stream) {
    const float* entity_emb    = (const float*)d_in[0];
    const float* user_emb      = (const float*)d_in[1];
    const float* latent_emb    = (const float*)d_in[2];
    const float* weight        = (const float*)d_in[3];
    const float* dwa           = (const float*)d_in[4];
    const float* interact_vals = (const float*)d_in[5];
    const int*   head          = (const int*)d_in[6];
    const int*   tail          = (const int*)d_in[7];
    const int*   edge_type     = (const int*)d_in[8];
    const int*   irows         = (const int*)d_in[9];
    const int*   icols         = (const int*)d_in[10];

    float* entity_agg = (float*)d_out;                                 // [N_ENTITIES,64]
    float* user_agg   = (float*)d_out + (size_t)N_ENTITIES * CHANNEL;  // [N_USERS,64]

    // workspace layout
    int*   wp_e   = (int*)d_ws;                   // NBE
    int*   wp_u   = wp_e + NBE;                   // NBU
    int*   coff_e = wp_u + NBU;                   // NBE+1
    int*   coff_u = coff_e + NBE + 1;             // NBU+1
    int*   pay_e  = coff_u + NBU + 1;             // N_EDGES
    int*   payA_u = pay_e + N_EDGES;              // N_INTER
    float* payB_u = (float*)(payA_u + N_INTER);   // N_INTER
    float* disen  = payB_u + N_INTER;             // 4*64
    u16*   emb16  = (u16*)(disen + N_FACTORS * CHANNEL);  // N_ENTITIES*64

    size_t need_bf16 = (size_t)((char*)(emb16 + (size_t)N_ENTITIES * CHANNEL) - (char*)d_ws);
    bool use_bf16 = (ws_size >= need_bf16);
    if (!use_bf16) emb16 = (u16*)d_ws;   // unused dummy

    hipMemsetAsync(wp_e, 0, (size_t)(NBE + NBU) * sizeof(int), stream);

    if (use_bf16) {
        prep_kernel<<<NCONV + 1 + NHIST, 256, 0, stream>>>(
            entity_emb, emb16, dwa, weight, disen, head, irows, wp_e, wp_u);
    } else {
        disen_kernel<<<1, 256, 0, stream>>>(dwa, weight, disen);
        hist_kernel<<<128, 1024, 0, stream>>>(head, irows, wp_e, wp_u);
    }

    scan_kernel<<<1, 1024, 0, stream>>>(wp_e, coff_e, wp_u, coff_u);

    scatter_kernel<<<NTBE + NTBU, 1024, 0, stream>>>(
        head, tail, edge_type, irows, icols, interact_vals,
        wp_e, pay_e, wp_u, payA_u, payB_u);

    if (use_bf16) {
        gather_kernel<true><<<NBE + NBU, 256, 0, stream>>>(
            entity_emb, emb16, weight, user_emb, latent_emb, disen,
            coff_e, pay_e, coff_u, payA_u, payB_u, entity_agg, user_agg);
    } else {
        gather_kernel<false><<<NBE + NBU, 256, 0, stream>>>(
            entity_emb, emb16, weight, user_emb, latent_emb, disen,
            coff_e, pay_e, coff_u, payA_u, payB_u, entity_agg, user_agg);
    }
}